// Round 2
// baseline (518.379 us; speedup 1.0000x reference)
//
#include <hip/hip_runtime.h>
#include <hip/hip_bf16.h>

// Problem constants: B=2, L=2048, D=1024, H=16, d_k=64
#define Hh 16
#define Ll 2048
#define Dd 1024
#define DK 64
#define Mm 4096  // B*L
#define Kk 1024
#define Nn 1024

typedef short bf16x8 __attribute__((ext_vector_type(8)));
typedef float f32x4 __attribute__((ext_vector_type(4)));

static __device__ __forceinline__ unsigned short f2bf(float f) {
    union { __hip_bfloat16 b; unsigned short u; } cv;
    cv.b = __float2bfloat16(f);
    return cv.u;
}

static __device__ __forceinline__ unsigned pack_bf2(float a, float b) {
    union { __hip_bfloat162 h; unsigned u; } cv;
    cv.h = __float22bfloat162_rn(make_float2(a, b));
    return cv.u;  // a in low 16, b in high 16
}

// async global->LDS, 16B per lane. LDS dest = wave-uniform base + lane*16 (HW).
static __device__ __forceinline__ void glds16(const ushort* g, ushort* l) {
    __builtin_amdgcn_global_load_lds((const __attribute__((address_space(1))) unsigned int*)g,
                                     (__attribute__((address_space(3))) unsigned int*)l,
                                     16, 0, 0);
}

// ---------------- fused fp32 -> bf16 casts (7 arrays, 1 launch) ----------------
__global__ __launch_bounds__(256) void cast_all(
    const float* __restrict__ q, const float* __restrict__ k, const float* __restrict__ v,
    const float* __restrict__ wq, const float* __restrict__ wk, const float* __restrict__ wv,
    const float* __restrict__ wo,
    ushort* __restrict__ qb, ushort* __restrict__ kb, ushort* __restrict__ vb,
    ushort* __restrict__ wqb, ushort* __restrict__ wkb, ushort* __restrict__ wvb,
    ushort* __restrict__ wob) {
    const int bx = blockIdx.x;
    const float4* s; ushort4* d; int base;
    if      (bx <  4096) { s = (const float4*)q;  d = (ushort4*)qb;  base = 0; }
    else if (bx <  8192) { s = (const float4*)k;  d = (ushort4*)kb;  base = 4096; }
    else if (bx < 12288) { s = (const float4*)v;  d = (ushort4*)vb;  base = 8192; }
    else if (bx < 13312) { s = (const float4*)wq; d = (ushort4*)wqb; base = 12288; }
    else if (bx < 14336) { s = (const float4*)wk; d = (ushort4*)wkb; base = 13312; }
    else if (bx < 15360) { s = (const float4*)wv; d = (ushort4*)wvb; base = 14336; }
    else                 { s = (const float4*)wo; d = (ushort4*)wob; base = 15360; }
    const int i = (bx - base) * 256 + threadIdx.x;
    float4 vv = s[i];
    ushort4 o;
    o.x = f2bf(vv.x); o.y = f2bf(vv.y); o.z = f2bf(vv.z); o.w = f2bf(vv.w);
    d[i] = o;
}

// ---------------- fused QKV projection GEMM ----------------
// C = A @ W^T + bias; A [4096,1024] bf16, W [1024,1024] bf16.
// z=0,1: scatter bf16 to [B,H,L,64] (Q,K). z=2: scatter bf16 to [B,H,64,L] (V^T).
// 128x128 tile, BK=32, global_load_lds staging, grid (8,32,3) = 768 blocks = 3/CU.
__global__ __launch_bounds__(256) void gemm_qkv(
    const ushort* __restrict__ A0, const ushort* __restrict__ A1, const ushort* __restrict__ A2,
    const ushort* __restrict__ W0, const ushort* __restrict__ W1, const ushort* __restrict__ W2,
    const float* __restrict__ b0, const float* __restrict__ b1, const float* __restrict__ b2,
    ushort* __restrict__ O0, ushort* __restrict__ O1, ushort* __restrict__ O2) {
    __shared__ __align__(16) ushort As[128 * 32];
    __shared__ __align__(16) ushort Bs[128 * 32];
    const int z = blockIdx.z;
    const ushort* A = (z == 0) ? A0 : (z == 1) ? A1 : A2;
    const ushort* W = (z == 0) ? W0 : (z == 1) ? W1 : W2;
    const float* bias = (z == 0) ? b0 : (z == 1) ? b1 : b2;
    ushort* Out = (z == 0) ? O0 : (z == 1) ? O1 : O2;

    const int t = threadIdx.x;
    const int wave = t >> 6, lane = t & 63;
    const int quad = lane >> 4, l15 = lane & 15;
    const int brow = blockIdx.y * 128, bcol = blockIdx.x * 128;
    const int wr = (wave >> 1) * 64, wc = (wave & 1) * 64;
    const int gr = wave * 16 + (lane >> 2);  // staging row within 64-row group
    const int gc = (lane & 3) * 8;           // staging col (elements)

    f32x4 acc[4][4] = {};

    for (int k0 = 0; k0 < Kk; k0 += 32) {
        __syncthreads();  // all waves done reading previous tile
        glds16(A + (size_t)(brow + gr) * Kk + k0 + gc,      As + wave * 512);
        glds16(A + (size_t)(brow + 64 + gr) * Kk + k0 + gc, As + 2048 + wave * 512);
        glds16(W + (size_t)(bcol + gr) * Kk + k0 + gc,      Bs + wave * 512);
        glds16(W + (size_t)(bcol + 64 + gr) * Kk + k0 + gc, Bs + 2048 + wave * 512);
        __syncthreads();  // vmcnt(0) drain before barrier -> LDS ready

        bf16x8 af[4], bfr[4];
#pragma unroll
        for (int i = 0; i < 4; i++)
            af[i] = *(const bf16x8*)(As + (wr + i * 16 + l15) * 32 + quad * 8);
#pragma unroll
        for (int j = 0; j < 4; j++)
            bfr[j] = *(const bf16x8*)(Bs + (wc + j * 16 + l15) * 32 + quad * 8);
#pragma unroll
        for (int i = 0; i < 4; i++)
#pragma unroll
            for (int j = 0; j < 4; j++)
                acc[i][j] = __builtin_amdgcn_mfma_f32_16x16x32_bf16(af[i], bfr[j], acc[i][j], 0, 0, 0);
    }

    // C/D layout: row = quad*4+r, col = l15 [verified]
#pragma unroll
    for (int i = 0; i < 4; i++)
#pragma unroll
        for (int j = 0; j < 4; j++) {
            const int n = bcol + wc + j * 16 + l15;
            const float bv = bias[n];
            const int h = n >> 6, dk = n & 63;
#pragma unroll
            for (int r = 0; r < 4; r++) {
                const int m = brow + wr + i * 16 + quad * 4 + r;
                const int b = m >> 11, l = m & 2047;
                const float v = acc[i][j][r] + bv;
                const size_t idx = (z < 2) ? (((size_t)(b * Hh + h) * Ll + l) * DK + dk)
                                           : (((size_t)(b * Hh + h) * DK + dk) * Ll + l);
                Out[idx] = f2bf(v);
            }
        }
}

// ---------------- output projection GEMM ----------------
// 64x128 tile, BK=32, grid (8,64) = 512 blocks = 2/CU, fp32 out + bias.
__global__ __launch_bounds__(256) void gemm_o(const ushort* __restrict__ A,
                                              const ushort* __restrict__ W,
                                              const float* __restrict__ bias,
                                              float* __restrict__ Out) {
    __shared__ __align__(16) ushort As[64 * 32];
    __shared__ __align__(16) ushort Bs[128 * 32];
    const int t = threadIdx.x;
    const int wave = t >> 6, lane = t & 63;
    const int quad = lane >> 4, l15 = lane & 15;
    const int brow = blockIdx.y * 64, bcol = blockIdx.x * 128;
    const int wr = (wave >> 1) * 32, wc = (wave & 1) * 64;
    const int gr = wave * 16 + (lane >> 2);
    const int gc = (lane & 3) * 8;

    f32x4 acc[2][4] = {};

    for (int k0 = 0; k0 < Kk; k0 += 32) {
        __syncthreads();
        glds16(A + (size_t)(brow + gr) * Kk + k0 + gc,      As + wave * 512);
        glds16(W + (size_t)(bcol + gr) * Kk + k0 + gc,      Bs + wave * 512);
        glds16(W + (size_t)(bcol + 64 + gr) * Kk + k0 + gc, Bs + 2048 + wave * 512);
        __syncthreads();

        bf16x8 af[2], bfr[4];
#pragma unroll
        for (int i = 0; i < 2; i++)
            af[i] = *(const bf16x8*)(As + (wr + i * 16 + l15) * 32 + quad * 8);
#pragma unroll
        for (int j = 0; j < 4; j++)
            bfr[j] = *(const bf16x8*)(Bs + (wc + j * 16 + l15) * 32 + quad * 8);
#pragma unroll
        for (int i = 0; i < 2; i++)
#pragma unroll
            for (int j = 0; j < 4; j++)
                acc[i][j] = __builtin_amdgcn_mfma_f32_16x16x32_bf16(af[i], bfr[j], acc[i][j], 0, 0, 0);
    }

#pragma unroll
    for (int i = 0; i < 2; i++)
#pragma unroll
        for (int j = 0; j < 4; j++) {
            const int n = bcol + wc + j * 16 + l15;
            const float bv = bias[n];
#pragma unroll
            for (int r = 0; r < 4; r++) {
                const int m = brow + wr + i * 16 + quad * 4 + r;
                Out[(size_t)m * Nn + n] = acc[i][j][r] + bv;
            }
        }
}

// ---------------- fused attention: S^T MFMA + static-max softmax, no LDS ----------------
// Q,K: [BH, L, 64] bf16. Vt: [BH, 64, L] bf16. Out AO: [B, L, H*64] bf16.
// Wave-independent: 16 q-rows per wave, 32-key tiles, register double-buffered.
// Static softmax offset M=24: p = exp2(s*log2e/8 + (band-24)*log2e); normalize at end.
__global__ __launch_bounds__(256) void attn_kernel(const ushort* __restrict__ Q,
                                                   const ushort* __restrict__ Kp,
                                                   const ushort* __restrict__ Vt,
                                                   ushort* __restrict__ Oout,
                                                   const int* __restrict__ masksize) {
    const int t = threadIdx.x;
    const int wave = t >> 6, lane = t & 63;
    const int quad = lane >> 4, l15 = lane & 15;
    const int blk = blockIdx.x;
    const int bh = blk >> 5;                       // 32 blocks per head
    const int q0 = (blk & 31) * 64 + wave * 16;    // 16 q-rows per wave
    const int half = masksize[0] >> 1;

    const ushort* Qb = Q + (size_t)bh * (Ll * DK);
    const ushort* Kb = Kp + (size_t)bh * (Ll * DK);
    const ushort* Vb = Vt + (size_t)bh * (DK * Ll);

    // Q fragments (B-operand of S^T MFMA): b[n=q=l15][k=d=quad*8+j]
    const bf16x8 qf0 = *(const bf16x8*)(Qb + (size_t)(q0 + l15) * DK + quad * 8);
    const bf16x8 qf1 = *(const bf16x8*)(Qb + (size_t)(q0 + l15) * DK + 32 + quad * 8);

    const float C1 = 0.125f * 1.44269504088896f;          // scale * log2(e)
    const float C2in = (1.0f - 24.0f) * 1.44269504088896f;
    const float C2out = -24.0f * 1.44269504088896f;
    const int q = q0 + l15;
    const unsigned wid = (unsigned)(2 * half);

    f32x4 Of[4] = {};   // O[row=q=quad*4+r][col=d=i*16+l15], unnormalized
    float rsum = 0.f;   // partial sum for column q=l15 over this lane's keys

    bf16x8 kfA[2][2], kfB[2][2];
    ushort4 vfA[2][4], vfB[2][4];

#define LOAD_TILE(kf, vf, key0) do {                                                   \
    _Pragma("unroll")                                                                  \
    for (int s = 0; s < 2; s++) {                                                      \
        const ushort* kr = Kb + (size_t)((key0) + s * 16 + l15) * DK + quad * 8;       \
        kf[s][0] = *(const bf16x8*)(kr);                                               \
        kf[s][1] = *(const bf16x8*)(kr + 32);                                          \
        _Pragma("unroll")                                                              \
        for (int i = 0; i < 4; i++)                                                    \
            vf[s][i] = *(const ushort4*)(Vb + (size_t)(i * 16 + l15) * Ll +            \
                                         (key0) + s * 16 + quad * 4);                  \
    }                                                                                  \
} while (0)

#define COMPUTE_TILE(kf, vf, key0) do {                                                \
    f32x4 z0 = {}, z1 = {};                                                            \
    z0 = __builtin_amdgcn_mfma_f32_16x16x32_bf16(kf[0][0], qf0, z0, 0, 0, 0);          \
    z0 = __builtin_amdgcn_mfma_f32_16x16x32_bf16(kf[0][1], qf1, z0, 0, 0, 0);          \
    z1 = __builtin_amdgcn_mfma_f32_16x16x32_bf16(kf[1][0], qf0, z1, 0, 0, 0);          \
    z1 = __builtin_amdgcn_mfma_f32_16x16x32_bf16(kf[1][1], qf1, z1, 0, 0, 0);          \
    const int tb = (key0) + quad * 4 + half - q;                                       \
    float p[8];                                                                        \
    _Pragma("unroll")                                                                  \
    for (int s = 0; s < 2; s++)                                                        \
        _Pragma("unroll")                                                              \
        for (int r = 0; r < 4; r++) {                                                  \
            const float zz = s ? z1[r] : z0[r];                                        \
            const unsigned tt = (unsigned)(tb + s * 16 + r);                           \
            const float c2 = (tt <= wid) ? C2in : C2out;                               \
            const float pp = exp2f(zz * C1 + c2);                                      \
            rsum += pp;                                                                \
            p[s * 4 + r] = pp;                                                         \
        }                                                                              \
    bf16x8 pf;                                                                         \
    ((unsigned*)&pf)[0] = pack_bf2(p[0], p[1]);                                        \
    ((unsigned*)&pf)[1] = pack_bf2(p[2], p[3]);                                        \
    ((unsigned*)&pf)[2] = pack_bf2(p[4], p[5]);                                        \
    ((unsigned*)&pf)[3] = pack_bf2(p[6], p[7]);                                        \
    _Pragma("unroll")                                                                  \
    for (int i = 0; i < 4; i++) {                                                      \
        bf16x8 vc;                                                                     \
        *(ushort4*)&vc = vf[0][i];                                                     \
        *((ushort4*)&vc + 1) = vf[1][i];                                               \
        Of[i] = __builtin_amdgcn_mfma_f32_16x16x32_bf16(pf, vc, Of[i], 0, 0, 0);       \
    }                                                                                  \
} while (0)

    LOAD_TILE(kfA, vfA, 0);
    for (int key0 = 0; key0 < Ll; key0 += 64) {
        LOAD_TILE(kfB, vfB, key0 + 32);
        COMPUTE_TILE(kfA, vfA, key0);
        if (key0 + 64 < Ll) LOAD_TILE(kfA, vfA, key0 + 64);
        COMPUTE_TILE(kfB, vfB, key0 + 32);
    }
#undef LOAD_TILE
#undef COMPUTE_TILE

    // reduce column sums across quads: after this every lane has total for q = lane&15
    rsum += __shfl_xor(rsum, 16);
    rsum += __shfl_xor(rsum, 32);
    float linv[4];
#pragma unroll
    for (int r = 0; r < 4; r++)
        linv[r] = 1.0f / __shfl(rsum, quad * 4 + r);  // sum for q = q0 + quad*4 + r

    const int b = bh >> 4, h = bh & 15;
#pragma unroll
    for (int i = 0; i < 4; i++)
#pragma unroll
        for (int r = 0; r < 4; r++) {
            const int qi = q0 + quad * 4 + r;
            Oout[((size_t)b * Ll + qi) * Dd + h * DK + i * 16 + l15] = f2bf(Of[i][r] * linv[r]);
        }
}

// ---------------- launch ----------------
extern "C" void kernel_launch(void* const* d_in, const int* in_sizes, int n_in,
                              void* d_out, int out_size, void* d_ws, size_t ws_size,
                              hipStream_t stream) {
    const float* query = (const float*)d_in[0];
    const float* key   = (const float*)d_in[1];
    const float* value = (const float*)d_in[2];
    const float* Wq = (const float*)d_in[3];
    const float* bq = (const float*)d_in[4];
    const float* Wk = (const float*)d_in[5];
    const float* bk = (const float*)d_in[6];
    const float* Wv = (const float*)d_in[7];
    const float* bv = (const float*)d_in[8];
    const float* Wo = (const float*)d_in[9];
    const float* bo = (const float*)d_in[10];
    const int* masksize = (const int*)d_in[11];

    char* ws = (char*)d_ws;
    const size_t MB = 1024 * 1024;
    ushort* qb  = (ushort*)(ws + 0 * MB);
    ushort* kbf = (ushort*)(ws + 8 * MB);
    ushort* vbf = (ushort*)(ws + 16 * MB);
    ushort* wqb = (ushort*)(ws + 24 * MB);
    ushort* wkb = (ushort*)(ws + 26 * MB);
    ushort* wvb = (ushort*)(ws + 28 * MB);
    ushort* wob = (ushort*)(ws + 30 * MB);
    ushort* Qp  = (ushort*)(ws + 32 * MB);  // [BH, L, 64]
    ushort* Kp  = (ushort*)(ws + 40 * MB);  // [BH, L, 64]
    ushort* Vt  = (ushort*)(ws + 48 * MB);  // [BH, 64, L]
    ushort* AO  = (ushort*)(ws + 56 * MB);  // [4096, 1024]

    cast_all<<<16384, 256, 0, stream>>>(query, key, value, Wq, Wk, Wv, Wo,
                                        qb, kbf, vbf, wqb, wkb, wvb, wob);

    gemm_qkv<<<dim3(8, 32, 3), 256, 0, stream>>>(qb, kbf, vbf,
                                                 wqb, wkb, wvb,
                                                 bq, bk, bv,
                                                 Qp, Kp, Vt);

    attn_kernel<<<1024, 256, 0, stream>>>(Qp, Kp, Vt, AO, masksize);

    gemm_o<<<dim3(8, 64), 256, 0, stream>>>(AO, wob, bo, (float*)d_out);
}

// Round 3
// 259.732 us; speedup vs baseline: 1.9958x; 1.9958x over previous
//
#include <hip/hip_runtime.h>
#include <hip/hip_bf16.h>

// Problem constants: B=2, L=2048, D=1024, H=16, d_k=64
#define Hh 16
#define Ll 2048
#define Dd 1024
#define DK 64
#define Mm 4096  // B*L
#define Kk 1024
#define Nn 1024

typedef short bf16x8 __attribute__((ext_vector_type(8)));
typedef float f32x4 __attribute__((ext_vector_type(4)));

static __device__ __forceinline__ unsigned short f2bf(float f) {
    union { __hip_bfloat16 b; unsigned short u; } cv;
    cv.b = __float2bfloat16(f);
    return cv.u;
}

static __device__ __forceinline__ unsigned pack_bf2(float a, float b) {
    union { __hip_bfloat162 h; unsigned u; } cv;
    cv.h = __float22bfloat162_rn(make_float2(a, b));
    return cv.u;  // a low 16, b high 16
}

// async global->LDS, 16B/lane. LDS dest = wave-uniform base + lane*16 (HW rule).
static __device__ __forceinline__ void glds16(const ushort* g, ushort* l) {
    __builtin_amdgcn_global_load_lds((const __attribute__((address_space(1))) unsigned int*)g,
                                     (__attribute__((address_space(3))) unsigned int*)l,
                                     16, 0, 0);
}

// ---------------- fused fp32 -> bf16 casts ----------------
__global__ __launch_bounds__(256) void cast_all(
    const float* __restrict__ q, const float* __restrict__ k, const float* __restrict__ v,
    const float* __restrict__ wq, const float* __restrict__ wk, const float* __restrict__ wv,
    const float* __restrict__ wo,
    ushort* __restrict__ qb, ushort* __restrict__ kb, ushort* __restrict__ vb,
    ushort* __restrict__ wqb, ushort* __restrict__ wkb, ushort* __restrict__ wvb,
    ushort* __restrict__ wob) {
    const int bx = blockIdx.x;
    const float4* s; ushort4* d; int base;
    if      (bx <  4096) { s = (const float4*)q;  d = (ushort4*)qb;  base = 0; }
    else if (bx <  8192) { s = (const float4*)k;  d = (ushort4*)kb;  base = 4096; }
    else if (bx < 12288) { s = (const float4*)v;  d = (ushort4*)vb;  base = 8192; }
    else if (bx < 13312) { s = (const float4*)wq; d = (ushort4*)wqb; base = 12288; }
    else if (bx < 14336) { s = (const float4*)wk; d = (ushort4*)wkb; base = 13312; }
    else if (bx < 15360) { s = (const float4*)wv; d = (ushort4*)wvb; base = 14336; }
    else                 { s = (const float4*)wo; d = (ushort4*)wob; base = 15360; }
    const int i = (bx - base) * 256 + threadIdx.x;
    float4 vv = s[i];
    ushort4 o;
    o.x = f2bf(vv.x); o.y = f2bf(vv.y); o.z = f2bf(vv.z); o.w = f2bf(vv.w);
    d[i] = o;
}

// ---------------- fused QKV projection GEMM ----------------
// C = A @ W^T + bias. All three outputs scatter bf16 to [BH, L, 64] (coalesced
// 32B runs across l15). 128x128 tile, BK=32, global_load_lds staging.
__global__ __launch_bounds__(256) void gemm_qkv(
    const ushort* __restrict__ A0, const ushort* __restrict__ A1, const ushort* __restrict__ A2,
    const ushort* __restrict__ W0, const ushort* __restrict__ W1, const ushort* __restrict__ W2,
    const float* __restrict__ b0, const float* __restrict__ b1, const float* __restrict__ b2,
    ushort* __restrict__ O0, ushort* __restrict__ O1, ushort* __restrict__ O2) {
    __shared__ __align__(16) ushort As[128 * 32];
    __shared__ __align__(16) ushort Bs[128 * 32];
    const int z = blockIdx.z;
    const ushort* A = (z == 0) ? A0 : (z == 1) ? A1 : A2;
    const ushort* W = (z == 0) ? W0 : (z == 1) ? W1 : W2;
    const float* bias = (z == 0) ? b0 : (z == 1) ? b1 : b2;
    ushort* Out = (z == 0) ? O0 : (z == 1) ? O1 : O2;

    const int t = threadIdx.x;
    const int wave = t >> 6, lane = t & 63;
    const int quad = lane >> 4, l15 = lane & 15;
    const int brow = blockIdx.y * 128, bcol = blockIdx.x * 128;
    const int wr = (wave >> 1) * 64, wc = (wave & 1) * 64;
    const int gr = wave * 16 + (lane >> 2);
    const int gc = (lane & 3) * 8;

    f32x4 acc[4][4] = {};

    for (int k0 = 0; k0 < Kk; k0 += 32) {
        __syncthreads();
        glds16(A + (size_t)(brow + gr) * Kk + k0 + gc,      As + wave * 512);
        glds16(A + (size_t)(brow + 64 + gr) * Kk + k0 + gc, As + 2048 + wave * 512);
        glds16(W + (size_t)(bcol + gr) * Kk + k0 + gc,      Bs + wave * 512);
        glds16(W + (size_t)(bcol + 64 + gr) * Kk + k0 + gc, Bs + 2048 + wave * 512);
        __syncthreads();

        bf16x8 af[4], bfr[4];
#pragma unroll
        for (int i = 0; i < 4; i++)
            af[i] = *(const bf16x8*)(As + (wr + i * 16 + l15) * 32 + quad * 8);
#pragma unroll
        for (int j = 0; j < 4; j++)
            bfr[j] = *(const bf16x8*)(Bs + (wc + j * 16 + l15) * 32 + quad * 8);
#pragma unroll
        for (int i = 0; i < 4; i++)
#pragma unroll
            for (int j = 0; j < 4; j++)
                acc[i][j] = __builtin_amdgcn_mfma_f32_16x16x32_bf16(af[i], bfr[j], acc[i][j], 0, 0, 0);
    }

    // C/D layout: row = quad*4+r, col = l15
#pragma unroll
    for (int i = 0; i < 4; i++)
#pragma unroll
        for (int j = 0; j < 4; j++) {
            const int n = bcol + wc + j * 16 + l15;
            const float bv = bias[n];
            const int h = n >> 6, dk = n & 63;
#pragma unroll
            for (int r = 0; r < 4; r++) {
                const int m = brow + wr + i * 16 + quad * 4 + r;
                const int b = m >> 11, l = m & 2047;
                Out[((size_t)(b * Hh + h) * Ll + l) * DK + dk] = f2bf(acc[i][j][r] + bv);
            }
        }
}

// ---------------- V transpose: [BH, L, 64] -> [BH, 64, L] ----------------
__global__ __launch_bounds__(256) void transp_v(const ushort* __restrict__ V1,
                                                ushort* __restrict__ Vt) {
    __shared__ ushort S[64][72];  // +8 pad breaks bank alignment on scattered writes
    const int bh = blockIdx.y;
    const int l0 = blockIdx.x * 64;
    const int t = threadIdx.x;
    const ushort* src = V1 + ((size_t)bh * Ll + l0) * DK;
    ushort* dst = Vt + (size_t)bh * DK * Ll + l0;
#pragma unroll
    for (int cc = 0; cc < 2; cc++) {
        const int c = t + cc * 256;          // 0..511
        const int l = c >> 3, dc = c & 7;
        ushort v8[8];
        *(uint4*)v8 = *(const uint4*)(src + (size_t)l * DK + dc * 8);
#pragma unroll
        for (int j = 0; j < 8; j++) S[dc * 8 + j][l] = v8[j];
    }
    __syncthreads();
#pragma unroll
    for (int cc = 0; cc < 2; cc++) {
        const int c = t + cc * 256;
        const int d = c >> 3, lc = c & 7;
        *(uint4*)(dst + (size_t)d * Ll + lc * 8) = *(const uint4*)(&S[d][lc * 8]);
    }
}

// ---------------- fused attention: LDS-staged, S^T MFMA, static-max softmax ----------------
// Block = 8 waves x 16 q = 128 q-rows, one head. 128-key tiles staged in LDS:
//   Ks: two panels [128 key][32 d] (m97 bank-balanced b128 reads)
//   Vs: [64 d][32 granules x 4 keys], granule-swizzled gp = g ^ (d&30)
//       -> PV b64 reads perfectly bank-balanced AND staging is a flat 16KB copy.
// Grid h-minor: bx = h + 32*qc -> all 16 blocks of a head share one XCD (b%8==h%8).
__global__ __launch_bounds__(512, 4) void attn_kernel(const ushort* __restrict__ Q,
                                                      const ushort* __restrict__ Kp,
                                                      const ushort* __restrict__ Vt,
                                                      ushort* __restrict__ Oout,
                                                      const int* __restrict__ masksize) {
    __shared__ __align__(16) ushort Ks[2 * 128 * 32];  // 16KB
    __shared__ __align__(16) ushort Vs[64 * 128];      // 16KB
    const int t = threadIdx.x;
    const int wave = t >> 6, lane = t & 63;
    const int quad = lane >> 4, l15 = lane & 15;
    const int bx = blockIdx.x;
    const int bh = bx & 31, qc = bx >> 5;
    const int q0 = qc * 128 + wave * 16;
    const int half = masksize[0] >> 1;
    const unsigned wid = (unsigned)(2 * half);

    const ushort* Qb = Q + (size_t)bh * (Ll * DK);
    const ushort* Kb = Kp + (size_t)bh * (Ll * DK);
    const ushort* Vb = Vt + (size_t)bh * (DK * Ll);

    // Q fragments (B-operand of S^T MFMA): b[n=q=l15][k=d=quad*8+j]
    const bf16x8 qf0 = *(const bf16x8*)(Qb + (size_t)(q0 + l15) * DK + quad * 8);
    const bf16x8 qf1 = *(const bf16x8*)(Qb + (size_t)(q0 + l15) * DK + 32 + quad * 8);

    // staging geometry (wave-uniform LDS bases, per-lane global addresses)
    const int kpan = wave >> 1;             // waves 0-3: K panel
    const int kcb  = (wave & 1) * 4;        // chunk base (16 keys/chunk)
    const int krow = lane >> 2;             // key within chunk
    const int kcol = kpan * 32 + (lane & 3) * 8;
    const int sbase = (wave - 4) * 4;       // waves 4-7: V store base
    const int vd_lo = lane >> 4;            // d within 4-row group
    const int vc16  = lane & 15;            // 16B chunk within row

    const float C1 = 0.125f * 1.44269504088896f;
    const float C2IN  = (1.0f - 24.0f) * 1.44269504088896f;
    const float C2OUT = -24.0f * 1.44269504088896f;

    f32x4 Of[4] = {};   // O[q = q0+quad*4+r][d = i*16+l15], unnormalized
    float rsum = 0.f;   // partial softmax denom for q = q0 + l15

    for (int kt = 0; kt < Ll; kt += 128) {
        __syncthreads();  // everyone done reading previous tile
        if (wave < 4) {
#pragma unroll
            for (int i = 0; i < 4; i++) {
                const int c = kcb + i;
                glds16(Kb + (size_t)(kt + c * 16 + krow) * DK + kcol,
                       Ks + (kpan * 128 + c * 16) * 32);
            }
        } else {
#pragma unroll
            for (int i = 0; i < 4; i++) {
                const int sidx = sbase + i;          // 0..15
                const int d = sidx * 4 + vd_lo;      // 0..63
                const int g0 = (2 * vc16) ^ (d & 30);
                glds16(Vb + (size_t)d * Ll + kt + g0 * 4, Vs + sidx * 512);
            }
        }
        __syncthreads();  // vmcnt(0) drain -> LDS ready

        // S^T = K_tile @ Q^T : 8 groups of 16 keys, k-dim 64 split in 2
        f32x4 z[8];
#pragma unroll
        for (int kg = 0; kg < 8; kg++) {
            const bf16x8 k0f = *(const bf16x8*)(Ks + (kg * 16 + l15) * 32 + quad * 8);
            const bf16x8 k1f = *(const bf16x8*)(Ks + 4096 + (kg * 16 + l15) * 32 + quad * 8);
            f32x4 zz = {};
            zz = __builtin_amdgcn_mfma_f32_16x16x32_bf16(k0f, qf0, zz, 0, 0, 0);
            zz = __builtin_amdgcn_mfma_f32_16x16x32_bf16(k1f, qf1, zz, 0, 0, 0);
            z[kg] = zz;
        }

        // band-mask mode for this wave/tile (wave-uniform)
        const bool allout = (kt + 127 < q0 - half) || (kt > q0 + 15 + half);
        const bool allin  = (kt >= q0 + 15 - half) && (kt + 127 <= q0 + half);
        const bool mixed  = !(allout || allin);
        const float c2u   = allin ? C2IN : C2OUT;
        const int tb = kt + half - q0 - l15 + quad * 4;  // tt = tb + kg*16 + r

#pragma unroll
        for (int s = 0; s < 4; s++) {
            float p[8];
#pragma unroll
            for (int g = 0; g < 2; g++)
#pragma unroll
                for (int r = 0; r < 4; r++) {
                    const float zz = z[2 * s + g][r];
                    float c2 = c2u;
                    if (mixed) {
                        const unsigned tt = (unsigned)(tb + (2 * s + g) * 16 + r);
                        c2 = (tt <= wid) ? C2IN : C2OUT;
                    }
                    const float pp = exp2f(zz * C1 + c2);
                    rsum += pp;
                    p[g * 4 + r] = pp;
                }
            bf16x8 pf;
            ((unsigned*)&pf)[0] = pack_bf2(p[0], p[1]);
            ((unsigned*)&pf)[1] = pack_bf2(p[2], p[3]);
            ((unsigned*)&pf)[2] = pack_bf2(p[4], p[5]);
            ((unsigned*)&pf)[3] = pack_bf2(p[6], p[7]);

#pragma unroll
            for (int i = 0; i < 4; i++) {
                const int d = i * 16 + l15;
                const int x4 = (d & 30) * 4;
                const int bi = d * 128;
                const ushort4 v1 = *(const ushort4*)(Vs + bi + (((s * 8 + quad) * 4) ^ x4));
                const ushort4 v2 = *(const ushort4*)(Vs + bi + (((s * 8 + 4 + quad) * 4) ^ x4));
                bf16x8 vc;
                *(ushort4*)&vc = v1;
                *((ushort4*)&vc + 1) = v2;
                Of[i] = __builtin_amdgcn_mfma_f32_16x16x32_bf16(pf, vc, Of[i], 0, 0, 0);
            }
        }
    }

    // softmax denom: lane has partial for q = l15; fold quads
    rsum += __shfl_xor(rsum, 16);
    rsum += __shfl_xor(rsum, 32);
    float linv[4];
#pragma unroll
    for (int r = 0; r < 4; r++)
        linv[r] = 1.0f / __shfl(rsum, quad * 4 + r);

    const int b = bh >> 4, h = bh & 15;
#pragma unroll
    for (int i = 0; i < 4; i++)
#pragma unroll
        for (int r = 0; r < 4; r++) {
            const int qi = q0 + quad * 4 + r;
            Oout[((size_t)b * Ll + qi) * Dd + h * DK + i * 16 + l15] = f2bf(Of[i][r] * linv[r]);
        }
}

// ---------------- output projection GEMM ----------------
__global__ __launch_bounds__(256) void gemm_o(const ushort* __restrict__ A,
                                              const ushort* __restrict__ W,
                                              const float* __restrict__ bias,
                                              float* __restrict__ Out) {
    __shared__ __align__(16) ushort As[64 * 32];
    __shared__ __align__(16) ushort Bs[128 * 32];
    const int t = threadIdx.x;
    const int wave = t >> 6, lane = t & 63;
    const int quad = lane >> 4, l15 = lane & 15;
    const int brow = blockIdx.y * 64, bcol = blockIdx.x * 128;
    const int wr = (wave >> 1) * 32, wc = (wave & 1) * 64;
    const int gr = wave * 16 + (lane >> 2);
    const int gc = (lane & 3) * 8;

    f32x4 acc[2][4] = {};

    for (int k0 = 0; k0 < Kk; k0 += 32) {
        __syncthreads();
        glds16(A + (size_t)(brow + gr) * Kk + k0 + gc,      As + wave * 512);
        glds16(W + (size_t)(bcol + gr) * Kk + k0 + gc,      Bs + wave * 512);
        glds16(W + (size_t)(bcol + 64 + gr) * Kk + k0 + gc, Bs + 2048 + wave * 512);
        __syncthreads();

        bf16x8 af[2], bfr[4];
#pragma unroll
        for (int i = 0; i < 2; i++)
            af[i] = *(const bf16x8*)(As + (wr + i * 16 + l15) * 32 + quad * 8);
#pragma unroll
        for (int j = 0; j < 4; j++)
            bfr[j] = *(const bf16x8*)(Bs + (wc + j * 16 + l15) * 32 + quad * 8);
#pragma unroll
        for (int i = 0; i < 2; i++)
#pragma unroll
            for (int j = 0; j < 4; j++)
                acc[i][j] = __builtin_amdgcn_mfma_f32_16x16x32_bf16(af[i], bfr[j], acc[i][j], 0, 0, 0);
    }

#pragma unroll
    for (int i = 0; i < 2; i++)
#pragma unroll
        for (int j = 0; j < 4; j++) {
            const int n = bcol + wc + j * 16 + l15;
            const float bv = bias[n];
#pragma unroll
            for (int r = 0; r < 4; r++) {
                const int m = brow + wr + i * 16 + quad * 4 + r;
                Out[(size_t)m * Nn + n] = acc[i][j][r] + bv;
            }
        }
}

// ---------------- launch ----------------
extern "C" void kernel_launch(void* const* d_in, const int* in_sizes, int n_in,
                              void* d_out, int out_size, void* d_ws, size_t ws_size,
                              hipStream_t stream) {
    const float* query = (const float*)d_in[0];
    const float* key   = (const float*)d_in[1];
    const float* value = (const float*)d_in[2];
    const float* Wq = (const float*)d_in[3];
    const float* bq = (const float*)d_in[4];
    const float* Wk = (const float*)d_in[5];
    const float* bk = (const float*)d_in[6];
    const float* Wv = (const float*)d_in[7];
    const float* bv = (const float*)d_in[8];
    const float* Wo = (const float*)d_in[9];
    const float* bo = (const float*)d_in[10];
    const int* masksize = (const int*)d_in[11];

    char* ws = (char*)d_ws;
    const size_t MB = 1024 * 1024;
    ushort* qb  = (ushort*)(ws + 0 * MB);   // consumed by gemm_qkv, then reused for Vt
    ushort* kbf = (ushort*)(ws + 8 * MB);
    ushort* vbf = (ushort*)(ws + 16 * MB);
    ushort* wqb = (ushort*)(ws + 24 * MB);
    ushort* wkb = (ushort*)(ws + 26 * MB);
    ushort* wvb = (ushort*)(ws + 28 * MB);
    ushort* wob = (ushort*)(ws + 30 * MB);
    ushort* Qp  = (ushort*)(ws + 32 * MB);  // [BH, L, 64]
    ushort* Kp  = (ushort*)(ws + 40 * MB);  // [BH, L, 64]
    ushort* V1  = (ushort*)(ws + 48 * MB);  // [BH, L, 64]
    ushort* AO  = (ushort*)(ws + 56 * MB);  // [4096, 1024]
    ushort* Vt  = (ushort*)(ws + 0 * MB);   // [BH, 64, L] (reuses qb region)

    cast_all<<<16384, 256, 0, stream>>>(query, key, value, Wq, Wk, Wv, Wo,
                                        qb, kbf, vbf, wqb, wkb, wvb, wob);

    gemm_qkv<<<dim3(8, 32, 3), 256, 0, stream>>>(qb, kbf, vbf,
                                                 wqb, wkb, wvb,
                                                 bq, bk, bv,
                                                 Qp, Kp, V1);

    transp_v<<<dim3(32, 32), 256, 0, stream>>>(V1, Vt);

    attn_kernel<<<512, 512, 0, stream>>>(Qp, Kp, Vt, AO, masksize);

    gemm_o<<<dim3(8, 64), 256, 0, stream>>>(AO, wob, bo, (float*)d_out);
}

// Round 4
// 230.861 us; speedup vs baseline: 2.2454x; 1.1251x over previous
//
#include <hip/hip_runtime.h>
#include <hip/hip_bf16.h>

// Problem constants: B=2, L=2048, D=1024, H=16, d_k=64
#define Hh 16
#define Ll 2048
#define Dd 1024
#define DK 64
#define Mm 4096  // B*L
#define Kk 1024
#define Nn 1024

typedef short bf16x8 __attribute__((ext_vector_type(8)));
typedef float f32x4 __attribute__((ext_vector_type(4)));

static __device__ __forceinline__ unsigned short f2bf(float f) {
    union { __hip_bfloat16 b; unsigned short u; } cv;
    cv.b = __float2bfloat16(f);
    return cv.u;
}

static __device__ __forceinline__ unsigned pack_bf2(float a, float b) {
    union { __hip_bfloat162 h; unsigned u; } cv;
    cv.h = __float22bfloat162_rn(make_float2(a, b));
    return cv.u;  // a low 16, b high 16
}

static __device__ __forceinline__ float fexp2(float x) {
    return __builtin_amdgcn_exp2f(x);  // single v_exp_f32 (no OCML wrapper)
}

// async global->LDS, 16B/lane. LDS dest = wave-uniform base + lane*16 (HW rule).
static __device__ __forceinline__ void glds16(const ushort* g, ushort* l) {
    __builtin_amdgcn_global_load_lds((const __attribute__((address_space(1))) unsigned int*)g,
                                     (__attribute__((address_space(3))) unsigned int*)l,
                                     16, 0, 0);
}

// ---------------- fused fp32 -> bf16 casts ----------------
__global__ __launch_bounds__(256) void cast_all(
    const float* __restrict__ q, const float* __restrict__ k, const float* __restrict__ v,
    const float* __restrict__ wq, const float* __restrict__ wk, const float* __restrict__ wv,
    const float* __restrict__ wo,
    ushort* __restrict__ qb, ushort* __restrict__ kb, ushort* __restrict__ vb,
    ushort* __restrict__ wqb, ushort* __restrict__ wkb, ushort* __restrict__ wvb,
    ushort* __restrict__ wob) {
    const int bx = blockIdx.x;
    const float4* s; ushort4* d; int base;
    if      (bx <  4096) { s = (const float4*)q;  d = (ushort4*)qb;  base = 0; }
    else if (bx <  8192) { s = (const float4*)k;  d = (ushort4*)kb;  base = 4096; }
    else if (bx < 12288) { s = (const float4*)v;  d = (ushort4*)vb;  base = 8192; }
    else if (bx < 13312) { s = (const float4*)wq; d = (ushort4*)wqb; base = 12288; }
    else if (bx < 14336) { s = (const float4*)wk; d = (ushort4*)wkb; base = 13312; }
    else if (bx < 15360) { s = (const float4*)wv; d = (ushort4*)wvb; base = 14336; }
    else                 { s = (const float4*)wo; d = (ushort4*)wob; base = 15360; }
    const int i = (bx - base) * 256 + threadIdx.x;
    float4 vv = s[i];
    ushort4 o;
    o.x = f2bf(vv.x); o.y = f2bf(vv.y); o.z = f2bf(vv.z); o.w = f2bf(vv.w);
    d[i] = o;
}

// ---------------- fused QKV projection GEMM ----------------
// C = A @ W^T + bias. z=0: Q, pre-scaled by 0.125*log2(e), scatter to [BH,L,64].
// z=1: K, scatter to [BH,L,64]. z=2: V, LDS-transposed epilogue -> [BH,64,L].
// 128x128 tile, BK=32, global_load_lds staging, grid (8,32,3) = 768 = 3/CU.
__global__ __launch_bounds__(256) void gemm_qkv(
    const ushort* __restrict__ A0, const ushort* __restrict__ A1, const ushort* __restrict__ A2,
    const ushort* __restrict__ W0, const ushort* __restrict__ W1, const ushort* __restrict__ W2,
    const float* __restrict__ b0, const float* __restrict__ b1, const float* __restrict__ b2,
    ushort* __restrict__ O0, ushort* __restrict__ O1, ushort* __restrict__ OVt) {
    __shared__ __align__(16) ushort SM[2 * 128 * 32];  // As | Bs ; reused as T in z==2 epilogue
    ushort* As = SM;
    ushort* Bs = SM + 4096;
    const int z = blockIdx.z;
    const ushort* A = (z == 0) ? A0 : (z == 1) ? A1 : A2;
    const ushort* W = (z == 0) ? W0 : (z == 1) ? W1 : W2;
    const float* bias = (z == 0) ? b0 : (z == 1) ? b1 : b2;

    const int t = threadIdx.x;
    const int wave = t >> 6, lane = t & 63;
    const int quad = lane >> 4, l15 = lane & 15;
    const int brow = blockIdx.y * 128, bcol = blockIdx.x * 128;
    const int wr = (wave >> 1) * 64, wc = (wave & 1) * 64;
    const int gr = wave * 16 + (lane >> 2);
    const int gc = (lane & 3) * 8;

    f32x4 acc[4][4] = {};

    for (int k0 = 0; k0 < Kk; k0 += 32) {
        __syncthreads();
        glds16(A + (size_t)(brow + gr) * Kk + k0 + gc,      As + wave * 512);
        glds16(A + (size_t)(brow + 64 + gr) * Kk + k0 + gc, As + 2048 + wave * 512);
        glds16(W + (size_t)(bcol + gr) * Kk + k0 + gc,      Bs + wave * 512);
        glds16(W + (size_t)(bcol + 64 + gr) * Kk + k0 + gc, Bs + 2048 + wave * 512);
        __syncthreads();

        bf16x8 af[4], bfr[4];
#pragma unroll
        for (int i = 0; i < 4; i++)
            af[i] = *(const bf16x8*)(As + (wr + i * 16 + l15) * 32 + quad * 8);
#pragma unroll
        for (int j = 0; j < 4; j++)
            bfr[j] = *(const bf16x8*)(Bs + (wc + j * 16 + l15) * 32 + quad * 8);
#pragma unroll
        for (int i = 0; i < 4; i++)
#pragma unroll
            for (int j = 0; j < 4; j++)
                acc[i][j] = __builtin_amdgcn_mfma_f32_16x16x32_bf16(af[i], bfr[j], acc[i][j], 0, 0, 0);
    }

    // C/D layout: row = quad*4+r, col = l15
    if (z < 2) {
        ushort* Out = (z == 0) ? O0 : O1;
        const float oscl = (z == 0) ? 0.18033688f : 1.0f;  // 0.125*log2(e) folded into Q
#pragma unroll
        for (int i = 0; i < 4; i++)
#pragma unroll
            for (int j = 0; j < 4; j++) {
                const int n = bcol + wc + j * 16 + l15;
                const float bv = bias[n];
                const int h = n >> 6, dk = n & 63;
#pragma unroll
                for (int r = 0; r < 4; r++) {
                    const int m = brow + wr + i * 16 + quad * 4 + r;
                    const int b = m >> 11, l = m & 2047;
                    Out[((size_t)(b * Hh + h) * Ll + l) * DK + dk] = f2bf((acc[i][j][r] + bv) * oscl);
                }
            }
    } else {
        // LDS transpose epilogue: emit V^T [BH, 64, L] with coalesced 16B stores.
        ushort* T = SM;  // T[32][136] = 4352 ushorts <= 8192
        const int b = brow >> 11;
        const int lbase = brow & 2047;
        const int npr = (wave & 1) * 16 + l15;   // column index within 32-wide chunk
#pragma unroll
        for (int j = 0; j < 4; j++) {
            __syncthreads();  // protect T (and last-iter As/Bs reads on j==0)
            const float bv = bias[bcol + wc + j * 16 + l15];
#pragma unroll
            for (int i = 0; i < 4; i++)
#pragma unroll
                for (int r = 0; r < 4; r++) {
                    const int m = wr + i * 16 + quad * 4 + r;
                    T[npr * 136 + m] = f2bf(acc[i][j][r] + bv);
                }
            __syncthreads();
#pragma unroll
            for (int cc = 0; cc < 2; cc++) {
                const int idx = t + cc * 256;    // 0..511
                const int ni = idx >> 4;         // 0..31
                const int ms = idx & 15;         // 0..15 (8-elem segment along m)
                const int n = bcol + (ni >> 4) * 64 + j * 16 + (ni & 15);
                const int hh = n >> 6, dk = n & 63;
                uint4 val = *(const uint4*)(T + ni * 136 + ms * 8);
                *(uint4*)(OVt + ((size_t)(b * Hh + hh) * DK + dk) * Ll + lbase + ms * 8) = val;
            }
        }
    }
}

// ---------------- fused attention: LDS-staged, S^T MFMA, static-max softmax ----------------
// Block = 4 waves x 32 q = 128 q-rows, one head. 128-key tiles in LDS:
//   Ks: two d-panels [128 key][32 d]; Vs: [64 d][granule-swizzled keys], gp = g ^ (d&30).
// Q pre-scaled by 0.125*log2e -> p = exp2(z + c2), single v_exp_f32 per score.
// Grid h-minor (bh = bx&31) -> head-XCD affinity. 512 blocks = 2/CU.
__global__ __launch_bounds__(256) void attn_kernel(const ushort* __restrict__ Q,
                                                   const ushort* __restrict__ Kp,
                                                   const ushort* __restrict__ Vt,
                                                   ushort* __restrict__ Oout,
                                                   const int* __restrict__ masksize) {
    __shared__ __align__(16) ushort Ks[2 * 128 * 32];  // 16KB
    __shared__ __align__(16) ushort Vs[64 * 128];      // 16KB
    const int t = threadIdx.x;
    const int wave = t >> 6, lane = t & 63;
    const int quad = lane >> 4, l15 = lane & 15;
    const int bx = blockIdx.x;
    const int bh = bx & 31, qc = bx >> 5;
    const int q0w = qc * 128 + wave * 32;    // this wave's 32 q-rows
    const int half = masksize[0] >> 1;
    const unsigned wid = (unsigned)(2 * half);

    const ushort* Qb = Q + (size_t)bh * (Ll * DK);
    const ushort* Kb = Kp + (size_t)bh * (Ll * DK);
    const ushort* Vb = Vt + (size_t)bh * (DK * Ll);

    // Q fragments (B-operand of S^T MFMA), two 16-q groups A/B
    const bf16x8 qA0 = *(const bf16x8*)(Qb + (size_t)(q0w + l15) * DK + quad * 8);
    const bf16x8 qA1 = *(const bf16x8*)(Qb + (size_t)(q0w + l15) * DK + 32 + quad * 8);
    const bf16x8 qB0 = *(const bf16x8*)(Qb + (size_t)(q0w + 16 + l15) * DK + quad * 8);
    const bf16x8 qB1 = *(const bf16x8*)(Qb + (size_t)(q0w + 16 + l15) * DK + 32 + quad * 8);

    const float C2IN  = (1.0f - 24.0f) * 1.44269504088896f;
    const float C2OUT = -24.0f * 1.44269504088896f;

    f32x4 OA[4] = {}, OB[4] = {};
    float rsA = 0.f, rsB = 0.f;

    // staging geometry
    const int krow = lane >> 2;              // key within 16-key chunk
    const int kcol8 = (lane & 3) * 8;        // d offset within 32-d panel (ushorts)
    const int vdl = lane >> 4;               // d within 4-row group
    const int vg0 = 2 * (lane & 15);         // LDS granule-pair base

    for (int kt = 0; kt < Ll; kt += 128) {
        __syncthreads();  // all waves done reading previous tile
        if (wave < 2) {
            const int cbase = wave * 4;
#pragma unroll
            for (int c = 0; c < 4; c++)
#pragma unroll
                for (int pan = 0; pan < 2; pan++)
                    glds16(Kb + (size_t)(kt + (cbase + c) * 16 + krow) * DK + pan * 32 + kcol8,
                           Ks + (pan * 128 + (cbase + c) * 16) * 32);
        } else {
            const int sb = (wave - 2) * 8;
#pragma unroll
            for (int i = 0; i < 8; i++) {
                const int sidx = sb + i;
                const int d = sidx * 4 + vdl;
                const int g0 = vg0 ^ (d & 30);
                glds16(Vb + (size_t)d * Ll + kt + g0 * 4, Vs + sidx * 512);
            }
        }
        __syncthreads();  // vmcnt(0) drain -> LDS ready

        // wave-uniform band-mask mode for this tile
        const int qlo = q0w, qhi = q0w + 31;
        const bool allout = (kt + 127 < qlo - half) || (kt > qhi + half);
        const bool allin  = (kt >= qhi - half) && (kt + 127 <= qlo + half);

#pragma unroll
        for (int s = 0; s < 4; s++) {
            // K fragments for 32 keys (kg = 2s, 2s+1)
            const bf16x8 kf00 = *(const bf16x8*)(Ks + ((2 * s) * 16 + l15) * 32 + quad * 8);
            const bf16x8 kf01 = *(const bf16x8*)(Ks + 4096 + ((2 * s) * 16 + l15) * 32 + quad * 8);
            const bf16x8 kf10 = *(const bf16x8*)(Ks + ((2 * s + 1) * 16 + l15) * 32 + quad * 8);
            const bf16x8 kf11 = *(const bf16x8*)(Ks + 4096 + ((2 * s + 1) * 16 + l15) * 32 + quad * 8);
            f32x4 zA0 = {}, zA1 = {}, zB0 = {}, zB1 = {};
            zA0 = __builtin_amdgcn_mfma_f32_16x16x32_bf16(kf00, qA0, zA0, 0, 0, 0);
            zA0 = __builtin_amdgcn_mfma_f32_16x16x32_bf16(kf01, qA1, zA0, 0, 0, 0);
            zA1 = __builtin_amdgcn_mfma_f32_16x16x32_bf16(kf10, qA0, zA1, 0, 0, 0);
            zA1 = __builtin_amdgcn_mfma_f32_16x16x32_bf16(kf11, qA1, zA1, 0, 0, 0);
            zB0 = __builtin_amdgcn_mfma_f32_16x16x32_bf16(kf00, qB0, zB0, 0, 0, 0);
            zB0 = __builtin_amdgcn_mfma_f32_16x16x32_bf16(kf01, qB1, zB0, 0, 0, 0);
            zB1 = __builtin_amdgcn_mfma_f32_16x16x32_bf16(kf10, qB0, zB1, 0, 0, 0);
            zB1 = __builtin_amdgcn_mfma_f32_16x16x32_bf16(kf11, qB1, zB1, 0, 0, 0);

            float pA[8], pB[8];
            if (allin || allout) {
                const float cu = allin ? C2IN : C2OUT;
#pragma unroll
                for (int g = 0; g < 2; g++)
#pragma unroll
                    for (int r = 0; r < 4; r++) {
                        pA[g * 4 + r] = fexp2((g ? zA1[r] : zA0[r]) + cu);
                        pB[g * 4 + r] = fexp2((g ? zB1[r] : zB0[r]) + cu);
                    }
            } else {
                const int kb = kt + s * 32 + quad * 4 + half;
#pragma unroll
                for (int g = 0; g < 2; g++)
#pragma unroll
                    for (int r = 0; r < 4; r++) {
                        const unsigned ttA = (unsigned)(kb + g * 16 + r - (q0w + l15));
                        const unsigned ttB = (unsigned)(kb + g * 16 + r - (q0w + 16 + l15));
                        pA[g * 4 + r] = fexp2((g ? zA1[r] : zA0[r]) + (ttA <= wid ? C2IN : C2OUT));
                        pB[g * 4 + r] = fexp2((g ? zB1[r] : zB0[r]) + (ttB <= wid ? C2IN : C2OUT));
                    }
            }
#pragma unroll
            for (int j = 0; j < 8; j++) { rsA += pA[j]; rsB += pB[j]; }

            bf16x8 pfA, pfB;
            ((unsigned*)&pfA)[0] = pack_bf2(pA[0], pA[1]);
            ((unsigned*)&pfA)[1] = pack_bf2(pA[2], pA[3]);
            ((unsigned*)&pfA)[2] = pack_bf2(pA[4], pA[5]);
            ((unsigned*)&pfA)[3] = pack_bf2(pA[6], pA[7]);
            ((unsigned*)&pfB)[0] = pack_bf2(pB[0], pB[1]);
            ((unsigned*)&pfB)[1] = pack_bf2(pB[2], pB[3]);
            ((unsigned*)&pfB)[2] = pack_bf2(pB[4], pB[5]);
            ((unsigned*)&pfB)[3] = pack_bf2(pB[6], pB[7]);

#pragma unroll
            for (int i = 0; i < 4; i++) {
                const int d = i * 16 + l15;
                const int x4 = (d & 30) * 4;
                const int bi = d * 128;
                const ushort4 v1 = *(const ushort4*)(Vs + bi + (((s * 8 + quad) * 4) ^ x4));
                const ushort4 v2 = *(const ushort4*)(Vs + bi + (((s * 8 + 4 + quad) * 4) ^ x4));
                bf16x8 vc;
                *(ushort4*)&vc = v1;
                *((ushort4*)&vc + 1) = v2;
                OA[i] = __builtin_amdgcn_mfma_f32_16x16x32_bf16(pfA, vc, OA[i], 0, 0, 0);
                OB[i] = __builtin_amdgcn_mfma_f32_16x16x32_bf16(pfB, vc, OB[i], 0, 0, 0);
            }
        }
    }

    // softmax denom: lane has partial for columns q0w+l15 (A) and q0w+16+l15 (B)
    rsA += __shfl_xor(rsA, 16); rsA += __shfl_xor(rsA, 32);
    rsB += __shfl_xor(rsB, 16); rsB += __shfl_xor(rsB, 32);
    float liA[4], liB[4];
#pragma unroll
    for (int r = 0; r < 4; r++) {
        liA[r] = 1.0f / __shfl(rsA, quad * 4 + r);
        liB[r] = 1.0f / __shfl(rsB, quad * 4 + r);
    }

    const int b = bh >> 4, h = bh & 15;
#pragma unroll
    for (int i = 0; i < 4; i++)
#pragma unroll
        for (int r = 0; r < 4; r++) {
            const int qa = q0w + quad * 4 + r;
            Oout[((size_t)b * Ll + qa) * Dd + h * DK + i * 16 + l15] = f2bf(OA[i][r] * liA[r]);
            Oout[((size_t)b * Ll + qa + 16) * Dd + h * DK + i * 16 + l15] = f2bf(OB[i][r] * liB[r]);
        }
}

// ---------------- output projection GEMM ----------------
__global__ __launch_bounds__(256) void gemm_o(const ushort* __restrict__ A,
                                              const ushort* __restrict__ W,
                                              const float* __restrict__ bias,
                                              float* __restrict__ Out) {
    __shared__ __align__(16) ushort As[64 * 32];
    __shared__ __align__(16) ushort Bs[128 * 32];
    const int t = threadIdx.x;
    const int wave = t >> 6, lane = t & 63;
    const int quad = lane >> 4, l15 = lane & 15;
    const int brow = blockIdx.y * 64, bcol = blockIdx.x * 128;
    const int wr = (wave >> 1) * 32, wc = (wave & 1) * 64;
    const int gr = wave * 16 + (lane >> 2);
    const int gc = (lane & 3) * 8;

    f32x4 acc[2][4] = {};

    for (int k0 = 0; k0 < Kk; k0 += 32) {
        __syncthreads();
        glds16(A + (size_t)(brow + gr) * Kk + k0 + gc,      As + wave * 512);
        glds16(W + (size_t)(bcol + gr) * Kk + k0 + gc,      Bs + wave * 512);
        glds16(W + (size_t)(bcol + 64 + gr) * Kk + k0 + gc, Bs + 2048 + wave * 512);
        __syncthreads();

        bf16x8 af[2], bfr[4];
#pragma unroll
        for (int i = 0; i < 2; i++)
            af[i] = *(const bf16x8*)(As + (wr + i * 16 + l15) * 32 + quad * 8);
#pragma unroll
        for (int j = 0; j < 4; j++)
            bfr[j] = *(const bf16x8*)(Bs + (wc + j * 16 + l15) * 32 + quad * 8);
#pragma unroll
        for (int i = 0; i < 2; i++)
#pragma unroll
            for (int j = 0; j < 4; j++)
                acc[i][j] = __builtin_amdgcn_mfma_f32_16x16x32_bf16(af[i], bfr[j], acc[i][j], 0, 0, 0);
    }

#pragma unroll
    for (int i = 0; i < 2; i++)
#pragma unroll
        for (int j = 0; j < 4; j++) {
            const int n = bcol + wc + j * 16 + l15;
            const float bv = bias[n];
#pragma unroll
            for (int r = 0; r < 4; r++) {
                const int m = brow + wr + i * 16 + quad * 4 + r;
                Out[(size_t)m * Nn + n] = acc[i][j][r] + bv;
            }
        }
}

// ---------------- launch ----------------
extern "C" void kernel_launch(void* const* d_in, const int* in_sizes, int n_in,
                              void* d_out, int out_size, void* d_ws, size_t ws_size,
                              hipStream_t stream) {
    const float* query = (const float*)d_in[0];
    const float* key   = (const float*)d_in[1];
    const float* value = (const float*)d_in[2];
    const float* Wq = (const float*)d_in[3];
    const float* bq = (const float*)d_in[4];
    const float* Wk = (const float*)d_in[5];
    const float* bk = (const float*)d_in[6];
    const float* Wv = (const float*)d_in[7];
    const float* bv = (const float*)d_in[8];
    const float* Wo = (const float*)d_in[9];
    const float* bo = (const float*)d_in[10];
    const int* masksize = (const int*)d_in[11];

    char* ws = (char*)d_ws;
    const size_t MB = 1024 * 1024;
    ushort* qb  = (ushort*)(ws + 0 * MB);
    ushort* kbf = (ushort*)(ws + 8 * MB);
    ushort* vbf = (ushort*)(ws + 16 * MB);
    ushort* wqb = (ushort*)(ws + 24 * MB);
    ushort* wkb = (ushort*)(ws + 26 * MB);
    ushort* wvb = (ushort*)(ws + 28 * MB);
    ushort* wob = (ushort*)(ws + 30 * MB);
    ushort* Qp  = (ushort*)(ws + 32 * MB);  // [BH, L, 64], pre-scaled by 0.125*log2e
    ushort* Kp  = (ushort*)(ws + 40 * MB);  // [BH, L, 64]
    ushort* Vt  = (ushort*)(ws + 48 * MB);  // [BH, 64, L]
    ushort* AO  = (ushort*)(ws + 56 * MB);  // [4096, 1024]

    cast_all<<<16384, 256, 0, stream>>>(query, key, value, Wq, Wk, Wv, Wo,
                                        qb, kbf, vbf, wqb, wkb, wvb, wob);

    gemm_qkv<<<dim3(8, 32, 3), 256, 0, stream>>>(qb, kbf, vbf,
                                                 wqb, wkb, wvb,
                                                 bq, bk, bv,
                                                 Qp, Kp, Vt);

    attn_kernel<<<512, 256, 0, stream>>>(Qp, Kp, Vt, AO, masksize);

    gemm_o<<<dim3(8, 64), 256, 0, stream>>>(AO, wob, bo, (float*)d_out);
}